// Round 6
// baseline (251.808 us; speedup 1.0000x reference)
//
#include <hip/hip_runtime.h>

namespace {

constexpr int B = 8, C = 4, K = 5;
constexpr int HW = 512 * 1024;   // pixels per (b,c) plane
constexpr int NG = HW / 4;       // float4 groups per plane (131072)
constexpr int GX = 256;          // blocks per batch
constexpr int NT = 256;          // threads per block
constexpr int NBLK = GX * B;     // 2048 blocks in pass2 grid
constexpr int STRIDE = GX * NT;  // 65536 = NG/2 -> exactly 2 groups/thread
constexpr float DV = 0.5f;       // DELTA_V
constexpr float DD = 3.0f;       // DELTA_D

// ws float layout:
//   p1t   [B*25][GX] : pass1 per-block partials (transposed)
//   p2t   [B*K][GX]  : pass2 per-block var partials (release-stored)
//   stats [B][25]    : {mean_c0..3, count} per (b,k) (release-stored)
//   cnt   1 x uint   : arrival counter (modulo-window, init-independent)
constexpr int P1_OFF = 0;
constexpr int P2_OFF = P1_OFF + B * 25 * GX;  // 51200
constexpr int ST_OFF = P2_OFF + B * K * GX;   // 61440
constexpr int CNT_OFF = ST_OFF + B * 25;      // 61640

__device__ __forceinline__ float wave_reduce(float v) {
#pragma unroll
  for (int m = 32; m; m >>= 1) v += __shfl_xor(v, m, 64);
  return v;
}

__device__ __forceinline__ float aload(const float* p) {  // coherent acquire
  return __hip_atomic_load(p, __ATOMIC_ACQUIRE, __HIP_MEMORY_SCOPE_AGENT);
}
__device__ __forceinline__ void astore(float* p, float v) {  // coherent rel.
  __hip_atomic_store(p, v, __ATOMIC_RELEASE, __HIP_MEMORY_SCOPE_AGENT);
}

// Pass 1: straight-line 2-group accumulate -> transposed per-block partials.
// (Cross-kernel boundary makes plain loads of these safe in pass2.)
__global__ __launch_bounds__(NT) void pass1_kernel(
    const float* __restrict__ emb, const int* __restrict__ lab,
    float* __restrict__ ws) {
  const int b = blockIdx.y, bx = blockIdx.x, tid = threadIdx.x;
  const int wv = tid >> 6, ln = tid & 63;
  const float4* __restrict__ ep =
      reinterpret_cast<const float4*>(emb + (size_t)b * C * HW);
  const int4* __restrict__ lp =
      reinterpret_cast<const int4*>(lab + (size_t)b * HW);
  const int g0 = bx * NT + tid, g1 = g0 + STRIDE;

  const int4 la = lp[g0], lb2 = lp[g1];
  const float4 a0 = ep[g0], a1 = ep[NG + g0], a2 = ep[2 * NG + g0],
               a3 = ep[3 * NG + g0];
  const float4 b0 = ep[g1], b1 = ep[NG + g1], b2 = ep[2 * NG + g1],
               b3 = ep[3 * NG + g1];

  float acc[25];  // [k][{c0..c3,cnt}] flat, compile-time indexed only
#pragma unroll
  for (int i = 0; i < 25; i++) acc[i] = 0.f;

  auto accum = [&](int l, float v0, float v1, float v2, float v3) {
#pragma unroll
    for (int k = 0; k < K; k++) {  // branchless predicated accumulate
      const float m = (l == k + 1) ? 1.f : 0.f;
      acc[k * 5 + 0] = fmaf(m, v0, acc[k * 5 + 0]);
      acc[k * 5 + 1] = fmaf(m, v1, acc[k * 5 + 1]);
      acc[k * 5 + 2] = fmaf(m, v2, acc[k * 5 + 2]);
      acc[k * 5 + 3] = fmaf(m, v3, acc[k * 5 + 3]);
      acc[k * 5 + 4] += m;
    }
  };
  accum(la.x, a0.x, a1.x, a2.x, a3.x);
  accum(la.y, a0.y, a1.y, a2.y, a3.y);
  accum(la.z, a0.z, a1.z, a2.z, a3.z);
  accum(la.w, a0.w, a1.w, a2.w, a3.w);
  accum(lb2.x, b0.x, b1.x, b2.x, b3.x);
  accum(lb2.y, b0.y, b1.y, b2.y, b3.y);
  accum(lb2.z, b0.z, b1.z, b2.z, b3.z);
  accum(lb2.w, b0.w, b1.w, b2.w, b3.w);

  __shared__ float red[4][25];
#pragma unroll
  for (int i = 0; i < 25; i++) {
    const float v = wave_reduce(acc[i]);
    if (ln == 0) red[wv][i] = v;
  }
  __syncthreads();
  if (tid < 25) {
    ws[P1_OFF + (size_t)(b * 25 + tid) * GX + bx] =
        red[0][tid] + red[1][tid] + red[2][tid] + red[3][tid];
  }
}

// Pass 2 (fused): stats fold + masked var sums + last-block finalize.
__global__ __launch_bounds__(NT) void pass2_fused_kernel(
    const float* __restrict__ emb, const int* __restrict__ lab,
    float* __restrict__ ws, float* __restrict__ out) {
  const int b = blockIdx.y, bx = blockIdx.x, tid = threadIdx.x;
  const int wv = tid >> 6, ln = tid & 63;

  // --- stats fold: reduce p1t rows for this batch (plain loads; safe
  //     across the kernel boundary) ---
  __shared__ float tot[25];
  for (int r = wv; r < 25; r += 4) {
    const float4 v = reinterpret_cast<const float4*>(
        ws + P1_OFF + (size_t)(b * 25 + r) * GX)[ln];
    float s = (v.x + v.y) + (v.z + v.w);
    s = wave_reduce(s);
    if (ln == 0) tot[r] = s;
  }
  __syncthreads();
  __shared__ float sm[K][C];
  if (tid < K * C) {
    const int k = tid / C, c = tid % C;
    sm[k][c] = tot[k * 5 + c] / tot[k * 5 + 4];
  }
  if (bx == 0 && tid < 25) {  // publish stats (release) for the finalize tail
    const float cnt = tot[(tid / 5) * 5 + 4];
    astore(&ws[ST_OFF + b * 25 + tid],
           (tid % 5 == 4) ? cnt : tot[tid] / cnt);
  }
  __syncthreads();

  // --- main masked relu(||e-mean||-DV)^2 accumulation ---
  const float4* __restrict__ ep =
      reinterpret_cast<const float4*>(emb + (size_t)b * C * HW);
  const int4* __restrict__ lp =
      reinterpret_cast<const int4*>(lab + (size_t)b * HW);
  const int g0 = bx * NT + tid, g1 = g0 + STRIDE;

  const int4 la = lp[g0], lb2 = lp[g1];
  const float4 a0 = ep[g0], a1 = ep[NG + g0], a2 = ep[2 * NG + g0],
               a3 = ep[3 * NG + g0];
  const float4 b0 = ep[g1], b1 = ep[NG + g1], b2 = ep[2 * NG + g1],
               b3 = ep[3 * NG + g1];

  float vacc[K] = {0.f, 0.f, 0.f, 0.f, 0.f};
  auto accum = [&](int l, float v0, float v1, float v2, float v3) {
    const int kk = (l > 0) ? (l - 1) : 0;  // safe index; l==0 masked below
    const float d0 = v0 - sm[kk][0];
    const float d1 = v1 - sm[kk][1];
    const float d2 = v2 - sm[kk][2];
    const float d3 = v3 - sm[kk][3];
    const float t =
        fmaxf(sqrtf(d0 * d0 + d1 * d1 + d2 * d2 + d3 * d3) - DV, 0.f);
    const float t2 = t * t;
#pragma unroll
    for (int k = 0; k < K; k++) vacc[k] += (l == k + 1) ? t2 : 0.f;
  };
  accum(la.x, a0.x, a1.x, a2.x, a3.x);
  accum(la.y, a0.y, a1.y, a2.y, a3.y);
  accum(la.z, a0.z, a1.z, a2.z, a3.z);
  accum(la.w, a0.w, a1.w, a2.w, a3.w);
  accum(lb2.x, b0.x, b1.x, b2.x, b3.x);
  accum(lb2.y, b0.y, b1.y, b2.y, b3.y);
  accum(lb2.z, b0.z, b1.z, b2.z, b3.z);
  accum(lb2.w, b0.w, b1.w, b2.w, b3.w);

  __shared__ float red2[4][K];
#pragma unroll
  for (int i = 0; i < K; i++) {
    const float v = wave_reduce(vacc[i]);
    if (ln == 0) red2[wv][i] = v;
  }
  __syncthreads();
  if (tid < K) {  // publish var partials (release)
    astore(&ws[P2_OFF + (size_t)(b * K + tid) * GX + bx],
           red2[0][tid] + red2[1][tid] + red2[2][tid] + red2[3][tid]);
  }
  __threadfence();  // belt-and-braces ordering before the counter
  __syncthreads();

  // --- arrival counter: exactly one block in each window of NBLK sees
  //     old % NBLK == NBLK-1, for ANY initial counter value ---
  __shared__ unsigned lastFlag;
  if (tid == 0) {
    unsigned* cnt = reinterpret_cast<unsigned*>(ws + CNT_OFF);
    const unsigned old = __hip_atomic_fetch_add(
        cnt, 1u, __ATOMIC_ACQ_REL, __HIP_MEMORY_SCOPE_AGENT);
    lastFlag = ((old % (unsigned)NBLK) == (unsigned)(NBLK - 1)) ? 1u : 0u;
  }
  __syncthreads();
  if (!lastFlag) return;

  // --- finalize (last block only): ALL cross-block reads use acquire loads
  //     (coherent, cache-bypassing) -> no stale-L1/L2 reads on replay ---
  __shared__ float tot2[B * K];
  for (int r = wv; r < B * K; r += 4) {
    const float* row = ws + P2_OFF + (size_t)r * GX;
    float s = (aload(&row[ln]) + aload(&row[ln + 64])) +
              (aload(&row[ln + 128]) + aload(&row[ln + 192]));
    s = wave_reduce(s);
    if (ln == 0) tot2[r] = s;
  }
  __shared__ float sstats[B * 25];
  if (tid < B * 25) sstats[tid] = aload(&ws[ST_OFF + tid]);
  __syncthreads();
  if (tid != 0) return;

  float v = 0.f, d = 0.f;
  for (int bb = 0; bb < B; bb++) {
    float m[K][C], cnt[K];
#pragma unroll
    for (int k = 0; k < K; k++) {
      cnt[k] = sstats[bb * 25 + k * 5 + 4];
#pragma unroll
      for (int c = 0; c < C; c++) m[k][c] = sstats[bb * 25 + k * 5 + c];
    }
    float s = 0.f;
#pragma unroll
    for (int k = 0; k < K; k++) s += tot2[bb * K + k] / cnt[k];
    float p = 0.f;
#pragma unroll
    for (int i = 0; i < K; i++) {
#pragma unroll
      for (int j = 0; j < K; j++) {
        if (i == j) continue;  // diagonal term is exactly 0
        float dd = 0.f;
#pragma unroll
        for (int c = 0; c < C; c++) {
          const float t = m[i][c] - m[j][c];
          dd += t * t;
        }
        const float r = fmaxf(DD - sqrtf(dd), 0.f);
        p += r * r;
      }
    }
    v = (v + s) / (float)K;
    d = (d + p) / (float)(2 * K * (K - 1));
  }
  out[0] = v / (float)B;
  out[1] = d / (float)B;
}

}  // namespace

extern "C" void kernel_launch(void* const* d_in, const int* in_sizes, int n_in,
                              void* d_out, int out_size, void* d_ws,
                              size_t ws_size, hipStream_t stream) {
  const float* emb = (const float*)d_in[0];
  const int* lab = (const int*)d_in[1];
  float* out = (float*)d_out;
  float* ws = (float*)d_ws;

  dim3 grid(GX, B);
  pass1_kernel<<<grid, NT, 0, stream>>>(emb, lab, ws);
  pass2_fused_kernel<<<grid, NT, 0, stream>>>(emb, lab, ws, out);
}

// Round 7
// 101.341 us; speedup vs baseline: 2.4848x; 2.4848x over previous
//
#include <hip/hip_runtime.h>

namespace {

constexpr int B = 8, C = 4, K = 5;
constexpr int HW = 512 * 1024;   // pixels per (b,c) plane
constexpr int NG = HW / 4;       // float4 groups per plane (131072)
constexpr int GX = 256;          // blocks per batch
constexpr int NT = 256;          // threads per block
constexpr int NBLK = GX * B;     // 2048 blocks in pass2 grid
constexpr int STRIDE = GX * NT;  // 65536 = NG/2 -> exactly 2 groups/thread
constexpr float DV = 0.5f;       // DELTA_V
constexpr float DD = 3.0f;       // DELTA_D
constexpr double FXS = 1099511627776.0;  // 2^40 fixed-point scale

// ws float layout:
//   p1t  [B*25][GX] : pass1 per-block partials (transposed; plain stores,
//                     read in pass2 across the kernel boundary = safe)
//   iacc [B] x u64  : fixed-point var-term accumulators (atomics only)
//   cnt  1 x uint   : arrival counter (atomics only)
// iacc/cnt are ZEROED BY PASS1 each call -> init-value independent.
constexpr int P1_OFF = 0;
constexpr int IACC_OFF = P1_OFF + B * 25 * GX;  // 51200 (16B-aligned)
constexpr int CNT_OFF = IACC_OFF + 2 * B;       // 51216

__device__ __forceinline__ float wave_reduce(float v) {
#pragma unroll
  for (int m = 32; m; m >>= 1) v += __shfl_xor(v, m, 64);
  return v;
}

// Pass 1: straight-line 2-group accumulate -> transposed per-block partials.
// Block (0,0) also zeroes the pass2 atomic slots (visible at dispatch end).
__global__ __launch_bounds__(NT) void pass1_kernel(
    const float* __restrict__ emb, const int* __restrict__ lab,
    float* __restrict__ ws) {
  const int b = blockIdx.y, bx = blockIdx.x, tid = threadIdx.x;
  const int wv = tid >> 6, ln = tid & 63;

  if (b == 0 && bx == 0) {  // reset atomic slots for pass2 (every call)
    if (tid < B) reinterpret_cast<unsigned long long*>(ws + IACC_OFF)[tid] = 0ull;
    if (tid == B) reinterpret_cast<unsigned*>(ws + CNT_OFF)[0] = 0u;
  }

  const float4* __restrict__ ep =
      reinterpret_cast<const float4*>(emb + (size_t)b * C * HW);
  const int4* __restrict__ lp =
      reinterpret_cast<const int4*>(lab + (size_t)b * HW);
  const int g0 = bx * NT + tid, g1 = g0 + STRIDE;

  const int4 la = lp[g0], lb2 = lp[g1];
  const float4 a0 = ep[g0], a1 = ep[NG + g0], a2 = ep[2 * NG + g0],
               a3 = ep[3 * NG + g0];
  const float4 b0 = ep[g1], b1 = ep[NG + g1], b2 = ep[2 * NG + g1],
               b3 = ep[3 * NG + g1];

  float acc[25];  // [k][{c0..c3,cnt}] flat, compile-time indexed only
#pragma unroll
  for (int i = 0; i < 25; i++) acc[i] = 0.f;

  auto accum = [&](int l, float v0, float v1, float v2, float v3) {
#pragma unroll
    for (int k = 0; k < K; k++) {  // branchless predicated accumulate
      const float m = (l == k + 1) ? 1.f : 0.f;
      acc[k * 5 + 0] = fmaf(m, v0, acc[k * 5 + 0]);
      acc[k * 5 + 1] = fmaf(m, v1, acc[k * 5 + 1]);
      acc[k * 5 + 2] = fmaf(m, v2, acc[k * 5 + 2]);
      acc[k * 5 + 3] = fmaf(m, v3, acc[k * 5 + 3]);
      acc[k * 5 + 4] += m;
    }
  };
  accum(la.x, a0.x, a1.x, a2.x, a3.x);
  accum(la.y, a0.y, a1.y, a2.y, a3.y);
  accum(la.z, a0.z, a1.z, a2.z, a3.z);
  accum(la.w, a0.w, a1.w, a2.w, a3.w);
  accum(lb2.x, b0.x, b1.x, b2.x, b3.x);
  accum(lb2.y, b0.y, b1.y, b2.y, b3.y);
  accum(lb2.z, b0.z, b1.z, b2.z, b3.z);
  accum(lb2.w, b0.w, b1.w, b2.w, b3.w);

  __shared__ float red[4][25];
#pragma unroll
  for (int i = 0; i < 25; i++) {
    const float v = wave_reduce(acc[i]);
    if (ln == 0) red[wv][i] = v;
  }
  __syncthreads();
  if (tid < 25) {
    ws[P1_OFF + (size_t)(b * 25 + tid) * GX + bx] =
        red[0][tid] + red[1][tid] + red[2][tid] + red[3][tid];
  }
}

// Pass 2 (fused): stats fold + masked var sums folded into fixed-point
// integer atomics (deterministic, fence-free) + last-block finalize.
__global__ __launch_bounds__(NT) void pass2_fused_kernel(
    const float* __restrict__ emb, const int* __restrict__ lab,
    float* __restrict__ ws, float* __restrict__ out) {
  const int b = blockIdx.y, bx = blockIdx.x, tid = threadIdx.x;
  const int wv = tid >> 6, ln = tid & 63;
  unsigned long long* iacc =
      reinterpret_cast<unsigned long long*>(ws + IACC_OFF);

  // --- stats fold: reduce this batch's 25 p1t rows (plain loads; written
  //     by pass1 -> safe across the kernel boundary) ---
  __shared__ float tot[25];
  for (int r = wv; r < 25; r += 4) {
    const float4 v = reinterpret_cast<const float4*>(
        ws + P1_OFF + (size_t)(b * 25 + r) * GX)[ln];
    float s = (v.x + v.y) + (v.z + v.w);
    s = wave_reduce(s);
    if (ln == 0) tot[r] = s;
  }
  __syncthreads();
  __shared__ float sm[K][C];
  if (tid < K * C) {
    const int k = tid / C, c = tid % C;
    sm[k][c] = tot[k * 5 + c] / tot[k * 5 + 4];
  }
  __syncthreads();

  // --- main masked relu(||e-mean||-DV)^2 accumulation ---
  const float4* __restrict__ ep =
      reinterpret_cast<const float4*>(emb + (size_t)b * C * HW);
  const int4* __restrict__ lp =
      reinterpret_cast<const int4*>(lab + (size_t)b * HW);
  const int g0 = bx * NT + tid, g1 = g0 + STRIDE;

  const int4 la = lp[g0], lb2 = lp[g1];
  const float4 a0 = ep[g0], a1 = ep[NG + g0], a2 = ep[2 * NG + g0],
               a3 = ep[3 * NG + g0];
  const float4 b0 = ep[g1], b1 = ep[NG + g1], b2 = ep[2 * NG + g1],
               b3 = ep[3 * NG + g1];

  float vacc[K] = {0.f, 0.f, 0.f, 0.f, 0.f};
  auto accum = [&](int l, float v0, float v1, float v2, float v3) {
    const int kk = (l > 0) ? (l - 1) : 0;  // safe index; l==0 masked below
    const float d0 = v0 - sm[kk][0];
    const float d1 = v1 - sm[kk][1];
    const float d2 = v2 - sm[kk][2];
    const float d3 = v3 - sm[kk][3];
    const float t =
        fmaxf(sqrtf(d0 * d0 + d1 * d1 + d2 * d2 + d3 * d3) - DV, 0.f);
    const float t2 = t * t;
#pragma unroll
    for (int k = 0; k < K; k++) vacc[k] += (l == k + 1) ? t2 : 0.f;
  };
  accum(la.x, a0.x, a1.x, a2.x, a3.x);
  accum(la.y, a0.y, a1.y, a2.y, a3.y);
  accum(la.z, a0.z, a1.z, a2.z, a3.z);
  accum(la.w, a0.w, a1.w, a2.w, a3.w);
  accum(lb2.x, b0.x, b1.x, b2.x, b3.x);
  accum(lb2.y, b0.y, b1.y, b2.y, b3.y);
  accum(lb2.z, b0.z, b1.z, b2.z, b3.z);
  accum(lb2.w, b0.w, b1.w, b2.w, b3.w);

  __shared__ float red2[4][K];
#pragma unroll
  for (int i = 0; i < K; i++) {
    const float v = wave_reduce(vacc[i]);
    if (ln == 0) red2[wv][i] = v;
  }
  __syncthreads();

  // --- fold this block's s_b contribution via 64-bit fixed-point atomic
  //     (integer add = associative = deterministic), then arrive. The
  //     s_waitcnt orders acc-add completion (at the coherence point)
  //     before the counter increment. No cache-maintenance fences. ---
  __shared__ unsigned lastFlag;
  if (tid == 0) {
    float sblk = 0.f;
#pragma unroll
    for (int k = 0; k < K; k++) {
      sblk += ((red2[0][k] + red2[1][k]) + (red2[2][k] + red2[3][k])) /
              tot[k * 5 + 4];
    }
    const unsigned long long fx =
        (unsigned long long)(long long)((double)sblk * FXS);
    atomicAdd(&iacc[b], fx);
    asm volatile("s_waitcnt vmcnt(0)" ::: "memory");
    unsigned* cnt = reinterpret_cast<unsigned*>(ws + CNT_OFF);
    const unsigned old = atomicAdd(cnt, 1u);  // zeroed by pass1 each call
    lastFlag = (old == (unsigned)(NBLK - 1)) ? 1u : 0u;
  }
  __syncthreads();
  if (!lastFlag) return;

  // --- finalize (unique last block): recompute ALL batches' stats from
  //     p1t (plain loads, pass1 data), read iacc via atomics (coherent) ---
  __shared__ float st[B * 25];
  for (int r = wv; r < B * 25; r += 4) {
    const float4 v =
        reinterpret_cast<const float4*>(ws + P1_OFF + (size_t)r * GX)[ln];
    float s = (v.x + v.y) + (v.z + v.w);
    s = wave_reduce(s);
    if (ln == 0) st[r] = s;
  }
  __shared__ float sb[B];
  if (tid < B) {
    const long long t2 = (long long)atomicAdd(&iacc[tid], 0ull);
    sb[tid] = (float)((double)t2 / FXS);
  }
  __syncthreads();
  if (tid != 0) return;

  float v = 0.f, d = 0.f;
  for (int bb = 0; bb < B; bb++) {
    float m[K][C];
#pragma unroll
    for (int k = 0; k < K; k++) {
      const float cnt = st[bb * 25 + k * 5 + 4];
#pragma unroll
      for (int c = 0; c < C; c++) m[k][c] = st[bb * 25 + k * 5 + c] / cnt;
    }
    float p = 0.f;
#pragma unroll
    for (int i = 0; i < K; i++) {
#pragma unroll
      for (int j = 0; j < K; j++) {
        if (i == j) continue;  // diagonal term is exactly 0
        float dd = 0.f;
#pragma unroll
        for (int c = 0; c < C; c++) {
          const float t = m[i][c] - m[j][c];
          dd += t * t;
        }
        const float r = fmaxf(DD - sqrtf(dd), 0.f);
        p += r * r;
      }
    }
    v = (v + sb[bb]) / (float)K;
    d = (d + p) / (float)(2 * K * (K - 1));
  }
  out[0] = v / (float)B;
  out[1] = d / (float)B;
}

}  // namespace

extern "C" void kernel_launch(void* const* d_in, const int* in_sizes, int n_in,
                              void* d_out, int out_size, void* d_ws,
                              size_t ws_size, hipStream_t stream) {
  const float* emb = (const float*)d_in[0];
  const int* lab = (const int*)d_in[1];
  float* out = (float*)d_out;
  float* ws = (float*)d_ws;

  dim3 grid(GX, B);
  pass1_kernel<<<grid, NT, 0, stream>>>(emb, lab, ws);
  pass2_fused_kernel<<<grid, NT, 0, stream>>>(emb, lab, ws, out);
}

// Round 8
// 82.590 us; speedup vs baseline: 3.0489x; 1.2270x over previous
//
#include <hip/hip_runtime.h>

namespace {

constexpr int B = 8, C = 4, K = 5;
constexpr int HW = 512 * 1024;  // pixels per (b,c) plane
constexpr int NG = HW / 4;      // float4 groups per plane (131072)
constexpr int NT = 256;         // threads per block
constexpr int GX1 = 256;        // pass1 blocks per batch (2 groups/thread)
constexpr int S1 = GX1 * NT;    // 65536
constexpr int GX2 = 128;        // pass2 blocks per batch (4 groups/thread)
constexpr int S2 = GX2 * NT;    // 32768
constexpr float DV = 0.5f;      // DELTA_V
constexpr float DD = 3.0f;      // DELTA_D
constexpr double FXS = 1099511627776.0;  // 2^40 fixed-point scale

// ws float layout. Atomic slots are PADDED: one 128B line each, so the
// longest same-line RMW chain is GX2=128 (per batch, batches in parallel).
//   p1t  [B*25][GX1] : pass1 per-block partials (plain stores; read in
//                      pass2 across the kernel boundary = safe)
//   iacc 8 x u64     : per-batch fixed-point var accumulators, 1 line each
//   bcnt 8 x u32     : per-batch arrival counters, 1 line each
//   gcnt 1 x u32     : global arrival counter (8 increments)
// All atomic slots are ZEROED BY PASS1 each call -> init-value independent.
constexpr int P1_OFF = 0;
constexpr int IACC_OFF = P1_OFF + B * 25 * GX1;  // 51200 (byte 204800, 128B-aligned)
constexpr int IACC_STR = 32;                     // floats per slot (128 B)
constexpr int BCNT_OFF = IACC_OFF + 8 * IACC_STR;  // 51456
constexpr int BCNT_STR = 32;
constexpr int GCNT_OFF = BCNT_OFF + 8 * BCNT_STR;  // 51712

__device__ __forceinline__ float wave_reduce(float v) {
#pragma unroll
  for (int m = 32; m; m >>= 1) v += __shfl_xor(v, m, 64);
  return v;
}

// Pass 1: straight-line 2-group accumulate -> transposed per-block partials.
// Block (0,0) also zeroes the pass2 atomic slots (visible at dispatch end).
__global__ __launch_bounds__(NT) void pass1_kernel(
    const float* __restrict__ emb, const int* __restrict__ lab,
    float* __restrict__ ws) {
  const int b = blockIdx.y, bx = blockIdx.x, tid = threadIdx.x;
  const int wv = tid >> 6, ln = tid & 63;

  if (b == 0 && bx == 0) {  // reset atomic slots for pass2 (every call)
    if (tid < 8) {
      reinterpret_cast<unsigned long long*>(ws + IACC_OFF +
                                            tid * IACC_STR)[0] = 0ull;
      reinterpret_cast<unsigned*>(ws + BCNT_OFF + tid * BCNT_STR)[0] = 0u;
    }
    if (tid == 8) reinterpret_cast<unsigned*>(ws + GCNT_OFF)[0] = 0u;
  }

  const float4* __restrict__ ep =
      reinterpret_cast<const float4*>(emb + (size_t)b * C * HW);
  const int4* __restrict__ lp =
      reinterpret_cast<const int4*>(lab + (size_t)b * HW);
  const int g0 = bx * NT + tid, g1 = g0 + S1;

  const int4 la = lp[g0], lb2 = lp[g1];
  const float4 a0 = ep[g0], a1 = ep[NG + g0], a2 = ep[2 * NG + g0],
               a3 = ep[3 * NG + g0];
  const float4 b0 = ep[g1], b1 = ep[NG + g1], b2 = ep[2 * NG + g1],
               b3 = ep[3 * NG + g1];

  float acc[25];  // [k][{c0..c3,cnt}] flat, compile-time indexed only
#pragma unroll
  for (int i = 0; i < 25; i++) acc[i] = 0.f;

  auto accum = [&](int l, float v0, float v1, float v2, float v3) {
#pragma unroll
    for (int k = 0; k < K; k++) {  // branchless predicated accumulate
      const float m = (l == k + 1) ? 1.f : 0.f;
      acc[k * 5 + 0] = fmaf(m, v0, acc[k * 5 + 0]);
      acc[k * 5 + 1] = fmaf(m, v1, acc[k * 5 + 1]);
      acc[k * 5 + 2] = fmaf(m, v2, acc[k * 5 + 2]);
      acc[k * 5 + 3] = fmaf(m, v3, acc[k * 5 + 3]);
      acc[k * 5 + 4] += m;
    }
  };
  accum(la.x, a0.x, a1.x, a2.x, a3.x);
  accum(la.y, a0.y, a1.y, a2.y, a3.y);
  accum(la.z, a0.z, a1.z, a2.z, a3.z);
  accum(la.w, a0.w, a1.w, a2.w, a3.w);
  accum(lb2.x, b0.x, b1.x, b2.x, b3.x);
  accum(lb2.y, b0.y, b1.y, b2.y, b3.y);
  accum(lb2.z, b0.z, b1.z, b2.z, b3.z);
  accum(lb2.w, b0.w, b1.w, b2.w, b3.w);

  __shared__ float red[4][25];
#pragma unroll
  for (int i = 0; i < 25; i++) {
    const float v = wave_reduce(acc[i]);
    if (ln == 0) red[wv][i] = v;
  }
  __syncthreads();
  if (tid < 25) {
    ws[P1_OFF + (size_t)(b * 25 + tid) * GX1 + bx] =
        red[0][tid] + red[1][tid] + red[2][tid] + red[3][tid];
  }
}

// Pass 2 (fused): stats fold + masked var sums -> per-batch fixed-point
// atomics (padded lines) -> batch counter -> global counter -> finalize.
__global__ __launch_bounds__(NT) void pass2_fused_kernel(
    const float* __restrict__ emb, const int* __restrict__ lab,
    float* __restrict__ ws, float* __restrict__ out) {
  const int b = blockIdx.y, bx = blockIdx.x, tid = threadIdx.x;
  const int wv = tid >> 6, ln = tid & 63;

  // --- stats fold: reduce this batch's 25 p1t rows (plain loads; pass1
  //     data is safe across the kernel boundary) ---
  __shared__ float tot[25];
  for (int r = wv; r < 25; r += 4) {
    const float4 v = reinterpret_cast<const float4*>(
        ws + P1_OFF + (size_t)(b * 25 + r) * GX1)[ln];
    float s = (v.x + v.y) + (v.z + v.w);
    s = wave_reduce(s);
    if (ln == 0) tot[r] = s;
  }
  __syncthreads();
  __shared__ float sm[K][C];
  if (tid < K * C) {
    const int k = tid / C, c = tid % C;
    sm[k][c] = tot[k * 5 + c] / tot[k * 5 + 4];
  }
  __syncthreads();

  // --- main masked relu(||e-mean||-DV)^2 accumulation (4 groups/thread,
  //     two straight-line 2-group segments) ---
  const float4* __restrict__ ep =
      reinterpret_cast<const float4*>(emb + (size_t)b * C * HW);
  const int4* __restrict__ lp =
      reinterpret_cast<const int4*>(lab + (size_t)b * HW);
  const int gbase = bx * NT + tid;

  float vacc[K] = {0.f, 0.f, 0.f, 0.f, 0.f};
  auto accum = [&](int l, float v0, float v1, float v2, float v3) {
    const int kk = (l > 0) ? (l - 1) : 0;  // safe index; l==0 masked below
    const float d0 = v0 - sm[kk][0];
    const float d1 = v1 - sm[kk][1];
    const float d2 = v2 - sm[kk][2];
    const float d3 = v3 - sm[kk][3];
    const float t =
        fmaxf(sqrtf(d0 * d0 + d1 * d1 + d2 * d2 + d3 * d3) - DV, 0.f);
    const float t2 = t * t;
#pragma unroll
    for (int k = 0; k < K; k++) vacc[k] += (l == k + 1) ? t2 : 0.f;
  };
#pragma unroll 1
  for (int seg = 0; seg < 2; seg++) {
    const int g0 = gbase + (2 * seg) * S2, g1 = g0 + S2;
    const int4 la = lp[g0], lb2 = lp[g1];
    const float4 a0 = ep[g0], a1 = ep[NG + g0], a2 = ep[2 * NG + g0],
                 a3 = ep[3 * NG + g0];
    const float4 b0 = ep[g1], b1 = ep[NG + g1], b2 = ep[2 * NG + g1],
                 b3 = ep[3 * NG + g1];
    accum(la.x, a0.x, a1.x, a2.x, a3.x);
    accum(la.y, a0.y, a1.y, a2.y, a3.y);
    accum(la.z, a0.z, a1.z, a2.z, a3.z);
    accum(la.w, a0.w, a1.w, a2.w, a3.w);
    accum(lb2.x, b0.x, b1.x, b2.x, b3.x);
    accum(lb2.y, b0.y, b1.y, b2.y, b3.y);
    accum(lb2.z, b0.z, b1.z, b2.z, b3.z);
    accum(lb2.w, b0.w, b1.w, b2.w, b3.w);
  }

  __shared__ float red2[4][K];
#pragma unroll
  for (int i = 0; i < K; i++) {
    const float v = wave_reduce(vacc[i]);
    if (ln == 0) red2[wv][i] = v;
  }
  __syncthreads();

  // --- fold s_b contribution via per-batch fixed-point atomic (own line),
  //     then batch counter (own line), then global counter. s_waitcnt
  //     orders each RMW's completion before the next; no cache fences. ---
  __shared__ unsigned lastFlag;
  if (tid == 0) {
    float sblk = 0.f;
#pragma unroll
    for (int k = 0; k < K; k++) {
      sblk += ((red2[0][k] + red2[1][k]) + (red2[2][k] + red2[3][k])) /
              tot[k * 5 + 4];
    }
    const unsigned long long fx =
        (unsigned long long)(long long)((double)sblk * FXS);
    atomicAdd(reinterpret_cast<unsigned long long*>(ws + IACC_OFF +
                                                    b * IACC_STR),
              fx);
    asm volatile("s_waitcnt vmcnt(0)" ::: "memory");
    unsigned* bcnt = reinterpret_cast<unsigned*>(ws + BCNT_OFF + b * BCNT_STR);
    const unsigned oldb = atomicAdd(bcnt, 1u);
    unsigned lf = 0u;
    if (oldb == (unsigned)(GX2 - 1)) {  // batch-last block
      asm volatile("s_waitcnt vmcnt(0)" ::: "memory");
      unsigned* gcnt = reinterpret_cast<unsigned*>(ws + GCNT_OFF);
      const unsigned oldg = atomicAdd(gcnt, 1u);
      lf = (oldg == (unsigned)(B - 1)) ? 1u : 0u;
    }
    lastFlag = lf;
  }
  __syncthreads();
  if (!lastFlag) return;

  // --- finalize (unique global-last block): recompute all batches' stats
  //     from p1t (plain loads), read iacc via relaxed agent atomic loads ---
  __shared__ float st[B * 25];
  for (int r = wv; r < B * 25; r += 4) {
    const float4 v =
        reinterpret_cast<const float4*>(ws + P1_OFF + (size_t)r * GX1)[ln];
    float s = (v.x + v.y) + (v.z + v.w);
    s = wave_reduce(s);
    if (ln == 0) st[r] = s;
  }
  __shared__ float sb[B];
  if (tid < B) {
    const unsigned long long raw = __hip_atomic_load(
        reinterpret_cast<const unsigned long long*>(ws + IACC_OFF +
                                                    tid * IACC_STR),
        __ATOMIC_RELAXED, __HIP_MEMORY_SCOPE_AGENT);
    sb[tid] = (float)((double)(long long)raw / FXS);
  }
  __syncthreads();
  if (tid != 0) return;

  float v = 0.f, d = 0.f;
  for (int bb = 0; bb < B; bb++) {
    float m[K][C];
#pragma unroll
    for (int k = 0; k < K; k++) {
      const float cnt = st[bb * 25 + k * 5 + 4];
#pragma unroll
      for (int c = 0; c < C; c++) m[k][c] = st[bb * 25 + k * 5 + c] / cnt;
    }
    float p = 0.f;
#pragma unroll
    for (int i = 0; i < K; i++) {
#pragma unroll
      for (int j = 0; j < K; j++) {
        if (i == j) continue;  // diagonal term is exactly 0
        float dd = 0.f;
#pragma unroll
        for (int c = 0; c < C; c++) {
          const float t = m[i][c] - m[j][c];
          dd += t * t;
        }
        const float r = fmaxf(DD - sqrtf(dd), 0.f);
        p += r * r;
      }
    }
    v = (v + sb[bb]) / (float)K;
    d = (d + p) / (float)(2 * K * (K - 1));
  }
  out[0] = v / (float)B;
  out[1] = d / (float)B;
}

}  // namespace

extern "C" void kernel_launch(void* const* d_in, const int* in_sizes, int n_in,
                              void* d_out, int out_size, void* d_ws,
                              size_t ws_size, hipStream_t stream) {
  const float* emb = (const float*)d_in[0];
  const int* lab = (const int*)d_in[1];
  float* out = (float*)d_out;
  float* ws = (float*)d_ws;

  pass1_kernel<<<dim3(GX1, B), NT, 0, stream>>>(emb, lab, ws);
  pass2_fused_kernel<<<dim3(GX2, B), NT, 0, stream>>>(emb, lab, ws, out);
}

// Round 9
// 57.603 us; speedup vs baseline: 4.3714x; 1.4338x over previous
//
#include <hip/hip_runtime.h>

namespace {

constexpr int B = 8, C = 4, K = 5;
constexpr int HW = 512 * 1024;  // pixels per (b,c) plane
constexpr int NG = HW / 4;      // float4 groups per plane (131072)
constexpr int NT = 256;         // threads per block
constexpr int GX1 = 256;        // pass1 blocks per batch (2 groups/thread)
constexpr int S1 = GX1 * NT;    // 65536
constexpr int GX2 = 128;        // pass2 blocks per batch (4 groups/thread)
constexpr int S2 = GX2 * NT;    // 32768
constexpr float DV = 0.5f;      // DELTA_V
constexpr float DD = 3.0f;      // DELTA_D
constexpr double FXS = 1099511627776.0;  // 2^40 fixed-point scale

// ws float layout. Every atomic slot sits on its own 128B line (max same-
// line chain = GX2 per batch; batches proceed in parallel). All atomic
// slots are ZEROED BY PASS1 block (0,0) each call -> init-independent.
//   p1t   [B*25][GX1] : pass1 per-block partials (plain; read across the
//                       kernel boundary = safe)
//   iacc  8 x u64     : per-batch fixed-point var accumulators
//   bcnt  8 x u32     : per-batch arrival counters
//   gcnt  1 x u32     : global arrival counter (8 increments)
//   stat  [B][32]     : 25 published stats per batch {means, count},
//                       single writer each (bx==0 block, wave 0, atomicAdd
//                       onto zero), read by finalize via atomic loads
constexpr int P1_OFF = 0;
constexpr int IACC_OFF = P1_OFF + B * 25 * GX1;    // 51200 (128B-aligned)
constexpr int IACC_STR = 32;                       // floats (128 B)
constexpr int BCNT_OFF = IACC_OFF + 8 * IACC_STR;  // 51456
constexpr int BCNT_STR = 32;
constexpr int GCNT_OFF = BCNT_OFF + 8 * BCNT_STR;  // 51712
constexpr int STAT_OFF = GCNT_OFF + 32;            // 51744
constexpr int STAT_STR = 32;                       // floats per batch

__device__ __forceinline__ float wave_reduce(float v) {
#pragma unroll
  for (int m = 32; m; m >>= 1) v += __shfl_xor(v, m, 64);
  return v;
}

// Pass 1: straight-line 2-group accumulate -> transposed per-block partials.
// Block (0,0) zeroes all pass2 atomic slots (visible at dispatch boundary).
__global__ __launch_bounds__(NT) void pass1_kernel(
    const float* __restrict__ emb, const int* __restrict__ lab,
    float* __restrict__ ws) {
  const int b = blockIdx.y, bx = blockIdx.x, tid = threadIdx.x;
  const int wv = tid >> 6, ln = tid & 63;

  if (b == 0 && bx == 0) {  // reset atomic slots for pass2 (every call)
    if (tid < 8) {
      reinterpret_cast<unsigned long long*>(ws + IACC_OFF +
                                            tid * IACC_STR)[0] = 0ull;
      reinterpret_cast<unsigned*>(ws + BCNT_OFF + tid * BCNT_STR)[0] = 0u;
    }
    if (tid == 8) reinterpret_cast<unsigned*>(ws + GCNT_OFF)[0] = 0u;
    ws[STAT_OFF + tid] = 0.f;  // NT == B*STAT_STR == 256
  }

  const float4* __restrict__ ep =
      reinterpret_cast<const float4*>(emb + (size_t)b * C * HW);
  const int4* __restrict__ lp =
      reinterpret_cast<const int4*>(lab + (size_t)b * HW);
  const int g0 = bx * NT + tid, g1 = g0 + S1;

  const int4 la = lp[g0], lb2 = lp[g1];
  const float4 a0 = ep[g0], a1 = ep[NG + g0], a2 = ep[2 * NG + g0],
               a3 = ep[3 * NG + g0];
  const float4 b0 = ep[g1], b1 = ep[NG + g1], b2 = ep[2 * NG + g1],
               b3 = ep[3 * NG + g1];

  float acc[25];  // [k][{c0..c3,cnt}] flat, compile-time indexed only
#pragma unroll
  for (int i = 0; i < 25; i++) acc[i] = 0.f;

  auto accum = [&](int l, float v0, float v1, float v2, float v3) {
#pragma unroll
    for (int k = 0; k < K; k++) {  // branchless predicated accumulate
      const float m = (l == k + 1) ? 1.f : 0.f;
      acc[k * 5 + 0] = fmaf(m, v0, acc[k * 5 + 0]);
      acc[k * 5 + 1] = fmaf(m, v1, acc[k * 5 + 1]);
      acc[k * 5 + 2] = fmaf(m, v2, acc[k * 5 + 2]);
      acc[k * 5 + 3] = fmaf(m, v3, acc[k * 5 + 3]);
      acc[k * 5 + 4] += m;
    }
  };
  accum(la.x, a0.x, a1.x, a2.x, a3.x);
  accum(la.y, a0.y, a1.y, a2.y, a3.y);
  accum(la.z, a0.z, a1.z, a2.z, a3.z);
  accum(la.w, a0.w, a1.w, a2.w, a3.w);
  accum(lb2.x, b0.x, b1.x, b2.x, b3.x);
  accum(lb2.y, b0.y, b1.y, b2.y, b3.y);
  accum(lb2.z, b0.z, b1.z, b2.z, b3.z);
  accum(lb2.w, b0.w, b1.w, b2.w, b3.w);

  __shared__ float red[4][25];
#pragma unroll
  for (int i = 0; i < 25; i++) {
    const float v = wave_reduce(acc[i]);
    if (ln == 0) red[wv][i] = v;
  }
  __syncthreads();
  if (tid < 25) {
    ws[P1_OFF + (size_t)(b * 25 + tid) * GX1 + bx] =
        red[0][tid] + red[1][tid] + red[2][tid] + red[3][tid];
  }
}

// Pass 2 (fused): stats fold (+publish by bx==0) + masked var sums ->
// per-batch fixed-point atomics -> counters -> tiny finalize (no bulk
// re-reads: everything it needs arrives via ~208 atomic scalar loads).
__global__ __launch_bounds__(NT) void pass2_fused_kernel(
    const float* __restrict__ emb, const int* __restrict__ lab,
    float* __restrict__ ws, float* __restrict__ out) {
  const int b = blockIdx.y, bx = blockIdx.x, tid = threadIdx.x;
  const int wv = tid >> 6, ln = tid & 63;

  // --- stats fold: reduce this batch's 25 p1t rows (plain loads; pass1
  //     data is safe across the kernel boundary) ---
  __shared__ float tot[25];
  for (int r = wv; r < 25; r += 4) {
    const float4 v = reinterpret_cast<const float4*>(
        ws + P1_OFF + (size_t)(b * 25 + r) * GX1)[ln];
    float s = (v.x + v.y) + (v.z + v.w);
    s = wave_reduce(s);
    if (ln == 0) tot[r] = s;
  }
  __syncthreads();
  __shared__ float sm[K][C];
  if (tid < K * C) {
    const int k = tid / C, c = tid % C;
    sm[k][c] = tot[k * 5 + c] / tot[k * 5 + 4];
  }
  if (bx == 0 && tid < 25) {  // publish stats: wave 0 -> covered by the
    const float cnt = tot[(tid / 5) * 5 + 4];  // vmcnt(0) below
    const float val = (tid % 5 == 4) ? cnt : tot[tid] / cnt;
    atomicAdd(&ws[STAT_OFF + b * STAT_STR + tid], val);  // slot is zeroed
  }
  __syncthreads();

  // --- main masked relu(||e-mean||-DV)^2 accumulation (4 groups/thread) ---
  const float4* __restrict__ ep =
      reinterpret_cast<const float4*>(emb + (size_t)b * C * HW);
  const int4* __restrict__ lp =
      reinterpret_cast<const int4*>(lab + (size_t)b * HW);
  const int gbase = bx * NT + tid;

  float vacc[K] = {0.f, 0.f, 0.f, 0.f, 0.f};
  auto accum = [&](int l, float v0, float v1, float v2, float v3) {
    const int kk = (l > 0) ? (l - 1) : 0;  // safe index; l==0 masked below
    const float d0 = v0 - sm[kk][0];
    const float d1 = v1 - sm[kk][1];
    const float d2 = v2 - sm[kk][2];
    const float d3 = v3 - sm[kk][3];
    const float t =
        fmaxf(sqrtf(d0 * d0 + d1 * d1 + d2 * d2 + d3 * d3) - DV, 0.f);
    const float t2 = t * t;
#pragma unroll
    for (int k = 0; k < K; k++) vacc[k] += (l == k + 1) ? t2 : 0.f;
  };
#pragma unroll 1
  for (int seg = 0; seg < 2; seg++) {
    const int g0 = gbase + (2 * seg) * S2, g1 = g0 + S2;
    const int4 la = lp[g0], lb2 = lp[g1];
    const float4 a0 = ep[g0], a1 = ep[NG + g0], a2 = ep[2 * NG + g0],
                 a3 = ep[3 * NG + g0];
    const float4 b0 = ep[g1], b1 = ep[NG + g1], b2 = ep[2 * NG + g1],
                 b3 = ep[3 * NG + g1];
    accum(la.x, a0.x, a1.x, a2.x, a3.x);
    accum(la.y, a0.y, a1.y, a2.y, a3.y);
    accum(la.z, a0.z, a1.z, a2.z, a3.z);
    accum(la.w, a0.w, a1.w, a2.w, a3.w);
    accum(lb2.x, b0.x, b1.x, b2.x, b3.x);
    accum(lb2.y, b0.y, b1.y, b2.y, b3.y);
    accum(lb2.z, b0.z, b1.z, b2.z, b3.z);
    accum(lb2.w, b0.w, b1.w, b2.w, b3.w);
  }

  __shared__ float red2[4][K];
#pragma unroll
  for (int i = 0; i < K; i++) {
    const float v = wave_reduce(vacc[i]);
    if (ln == 0) red2[wv][i] = v;
  }
  __syncthreads();

  // --- fold s_b via per-batch fixed-point atomic, then counters. wave-0
  //     vmcnt(0) drains BOTH the stat publishes and the iacc add before
  //     the arrival increment; no cache-maintenance fences anywhere. ---
  __shared__ unsigned lastFlag;
  if (tid == 0) {
    float sblk = 0.f;
#pragma unroll
    for (int k = 0; k < K; k++) {
      sblk += ((red2[0][k] + red2[1][k]) + (red2[2][k] + red2[3][k])) /
              tot[k * 5 + 4];
    }
    const unsigned long long fx =
        (unsigned long long)(long long)((double)sblk * FXS);
    atomicAdd(
        reinterpret_cast<unsigned long long*>(ws + IACC_OFF + b * IACC_STR),
        fx);
    asm volatile("s_waitcnt vmcnt(0)" ::: "memory");
    unsigned* bcnt = reinterpret_cast<unsigned*>(ws + BCNT_OFF + b * BCNT_STR);
    const unsigned oldb = atomicAdd(bcnt, 1u);
    unsigned lf = 0u;
    if (oldb == (unsigned)(GX2 - 1)) {  // batch-last block
      asm volatile("s_waitcnt vmcnt(0)" ::: "memory");
      unsigned* gcnt = reinterpret_cast<unsigned*>(ws + GCNT_OFF);
      const unsigned oldg = atomicAdd(gcnt, 1u);
      lf = (oldg == (unsigned)(B - 1)) ? 1u : 0u;
    }
    lastFlag = lf;
  }
  __syncthreads();
  if (!lastFlag) return;

  // --- finalize (unique global-last block): ~208 scalar atomic loads,
  //     all in flight at once -> ~2 us, no bulk latency-bound re-reads ---
  __shared__ float st[B * 25];
  if (tid < B * 25) {
    st[tid] = __hip_atomic_load(
        &ws[STAT_OFF + (tid / 25) * STAT_STR + (tid % 25)], __ATOMIC_RELAXED,
        __HIP_MEMORY_SCOPE_AGENT);
  }
  __shared__ float sb[B];
  if (tid < B) {
    const unsigned long long raw = __hip_atomic_load(
        reinterpret_cast<const unsigned long long*>(ws + IACC_OFF +
                                                    tid * IACC_STR),
        __ATOMIC_RELAXED, __HIP_MEMORY_SCOPE_AGENT);
    sb[tid] = (float)((double)(long long)raw / FXS);
  }
  __syncthreads();
  if (tid != 0) return;

  float v = 0.f, d = 0.f;
  for (int bb = 0; bb < B; bb++) {
    float m[K][C];  // st already holds means (and counts at slot 4)
#pragma unroll
    for (int k = 0; k < K; k++) {
#pragma unroll
      for (int c = 0; c < C; c++) m[k][c] = st[bb * 25 + k * 5 + c];
    }
    float p = 0.f;
#pragma unroll
    for (int i = 0; i < K; i++) {
#pragma unroll
      for (int j = 0; j < K; j++) {
        if (i == j) continue;  // diagonal term is exactly 0
        float dd = 0.f;
#pragma unroll
        for (int c = 0; c < C; c++) {
          const float t = m[i][c] - m[j][c];
          dd += t * t;
        }
        const float r = fmaxf(DD - sqrtf(dd), 0.f);
        p += r * r;
      }
    }
    v = (v + sb[bb]) / (float)K;
    d = (d + p) / (float)(2 * K * (K - 1));
  }
  out[0] = v / (float)B;
  out[1] = d / (float)B;
}

}  // namespace

extern "C" void kernel_launch(void* const* d_in, const int* in_sizes, int n_in,
                              void* d_out, int out_size, void* d_ws,
                              size_t ws_size, hipStream_t stream) {
  const float* emb = (const float*)d_in[0];
  const int* lab = (const int*)d_in[1];
  float* out = (float*)d_out;
  float* ws = (float*)d_ws;

  pass1_kernel<<<dim3(GX1, B), NT, 0, stream>>>(emb, lab, ws);
  pass2_fused_kernel<<<dim3(GX2, B), NT, 0, stream>>>(emb, lab, ws, out);
}